// Round 1
// baseline (467.390 us; speedup 1.0000x reference)
//
#include <hip/hip_runtime.h>

#define XD 48
#define VV (48*48*48)      // 110592
#define BB 2
#define NPTS 20000
#define MAXF 5000
#define COUT 32

static inline size_t align_up(size_t v, size_t a){ return (v + a - 1) & ~(a - 1); }

// ---------------- scatter (last-point-wins via atomicMax winner) ----------------
__global__ void scatter_winner_k(const int* __restrict__ coords, int* __restrict__ winner)
{
    int t = blockIdx.x*blockDim.x + threadIdx.x;
    if (t >= BB*NPTS) return;
    int b = t / NPTS, n = t % NPTS;
    const int* c = coords + (size_t)t*3;
    int vox = (c[0]*48 + c[1])*48 + c[2];
    atomicMax(&winner[b*VV + vox], n);
}

__global__ void scatter_write_k(const int* __restrict__ coords, const float* __restrict__ feat,
                                const int* __restrict__ winner, float* __restrict__ grid0,
                                unsigned char* __restrict__ occ0)
{
    int t = blockIdx.x*blockDim.x + threadIdx.x;
    if (t >= BB*NPTS) return;
    int b = t / NPTS, n = t % NPTS;
    const int* c = coords + (size_t)t*3;
    int vox = (c[0]*48 + c[1])*48 + c[2];
    int gi = b*VV + vox;
    occ0[gi] = 1;
    if (winner[gi] == n) {
        const float* f = feat + (size_t)t*16;
        float* g = grid0 + (size_t)gi*16;
        #pragma unroll
        for (int cc=0; cc<16; ++cc) g[cc] = f[cc];
    }
}

// ---------------- 3x3x3 binary dilation ----------------
__global__ void dilate_k(const unsigned char* __restrict__ in, unsigned char* __restrict__ out)
{
    int t = blockIdx.x*blockDim.x + threadIdx.x;
    if (t >= BB*VV) return;
    int b = t / VV, v = t % VV;
    int x = v / 2304, y = (v / 48) % 48, z = v % 48;
    unsigned char r = 0;
    for (int dx=-1; dx<=1; ++dx){ int xx=x+dx; if ((unsigned)xx >= 48u) continue;
      for (int dy=-1; dy<=1; ++dy){ int yy=y+dy; if ((unsigned)yy >= 48u) continue;
        const unsigned char* p = in + (size_t)b*VV + (size_t)(xx*48+yy)*48;
        for (int dz=-1; dz<=1; ++dz){ int zz=z+dz; if ((unsigned)zz >= 48u) continue;
          r |= p[zz];
        }}}
    out[t] = r ? 1 : 0;
}

// ---------------- occ2 per-x-slice active counts ----------------
__global__ void slice_count_k(const unsigned char* __restrict__ occ2, int* __restrict__ counts)
{
    int b = blockIdx.x / 48, x = blockIdx.x % 48;
    __shared__ int s;
    if (threadIdx.x == 0) s = 0;
    __syncthreads();
    int cnt = 0;
    for (int i = threadIdx.x; i < 2304; i += blockDim.x)
        cnt += occ2[(size_t)b*VV + x*2304 + i] ? 1 : 0;
    atomicAdd(&s, cnt);
    __syncthreads();
    if (threadIdx.x == 0) counts[blockIdx.x] = s;
}

// ---------------- prefix over 48 slices; derive n_out and x-limit ----------------
__global__ void prefix_k(const int* __restrict__ counts, int* __restrict__ base,
                         int* __restrict__ nout, int* __restrict__ xl5)
{
    int b = threadIdx.x;
    if (b >= BB) return;
    int tot = 0;
    for (int x=0; x<48; ++x) tot += counts[b*48+x];
    int nsel = tot < MAXF ? tot : MAXF;
    int run = 0;
    for (int x=0; x<48; ++x) { base[b*48+x] = run; run += counts[b*48+x]; }
    int cum = 0, xl = 0;
    for (int x=0; x<48; ++x) { cum += counts[b*48+x]; if (cum >= nsel) { xl = x; break; } }
    if (nsel == 0) xl = 0;
    nout[b] = nsel;
    xl5[b] = xl;
}

// ---------------- ordered compaction of first MAXF occ2-active voxels ----------------
__global__ void compact_k(const unsigned char* __restrict__ occ2, const int* __restrict__ base,
                          int* __restrict__ oidx)
{
    int b = blockIdx.x / 48, x = blockIdx.x % 48;
    __shared__ int wtot[4];
    __shared__ int chunk_base;
    int tid = threadIdx.x;
    if (tid == 0) chunk_base = base[b*48 + x];
    __syncthreads();
    for (int ch = 0; ch < 9; ++ch) {           // 9*256 = 2304 voxels per slice
        int i = ch*256 + tid;
        int vox = x*2304 + i;
        bool a = occ2[(size_t)b*VV + vox] != 0;
        unsigned long long m = __ballot(a);
        int lane = tid & 63, wv = tid >> 6;
        int rank = __popcll(m & ((1ull << lane) - 1ull));
        if (lane == 0) wtot[wv] = __popcll(m);
        __syncthreads();
        int woff = 0;
        for (int k=0; k<wv; ++k) woff += wtot[k];
        int pos = chunk_base + woff + rank;
        if (a && pos < MAXF) oidx[b*MAXF + pos] = vox;
        __syncthreads();
        if (tid == 0) chunk_base += wtot[0]+wtot[1]+wtot[2]+wtot[3];
        __syncthreads();
    }
}

// ---------------- 27-tap conv accumulator (one (voxel,cout) per thread) ----------------
template<int C1>
__device__ __forceinline__ float conv_acc(const float* __restrict__ in, const float* __restrict__ w,
                                          int b, int x, int y, int z, int co)
{
    float acc = 0.f;
    for (int dx=0; dx<3; ++dx){ int xx = x+dx-1; if ((unsigned)xx >= 48u) continue;
      for (int dy=0; dy<3; ++dy){ int yy = y+dy-1; if ((unsigned)yy >= 48u) continue;
        const float* inb = in + ((size_t)b*VV + (size_t)(xx*48+yy)*48)*C1;
        const float* wb  = w + (size_t)(dx*9 + dy*3)*C1*COUT;
        for (int dz=0; dz<3; ++dz){ int zz = z+dz-1; if ((unsigned)zz >= 48u) continue;
            const float* ip = inb + (size_t)zz*C1;
            const float* wp = wb + (size_t)dz*C1*COUT + co;
            #pragma unroll
            for (int c4=0; c4<C1/4; ++c4){
                float4 iv = *(const float4*)(ip + c4*4);
                acc = fmaf(iv.x, wp[(c4*4+0)*COUT], acc);
                acc = fmaf(iv.y, wp[(c4*4+1)*COUT], acc);
                acc = fmaf(iv.z, wp[(c4*4+2)*COUT], acc);
                acc = fmaf(iv.w, wp[(c4*4+3)*COUT], acc);
            }
        }}}
    return acc;
}

// ---------------- conv layer over slab x<=xl5+off; COMPACT = active-site-only ----------------
template<int C1, bool RELU, bool COMPACT>
__global__ void conv_k(const float* __restrict__ in, float* __restrict__ out,
                       const float* __restrict__ w, const unsigned char* __restrict__ mask,
                       const int* __restrict__ xl5, int off)
{
    int y = blockIdx.x, x = blockIdx.y, b = blockIdx.z;
    int lim = xl5[b] + off; if (lim > 47) lim = 47;
    if (x > lim) return;

    __shared__ int alist[48];
    __shared__ int nact_s;
    int tid = threadIdx.x;
    int rowv = x*2304 + y*48;

    if (COMPACT) {
        if (tid < 64) {
            bool a = (tid < 48) && mask[(size_t)b*VV + rowv + tid];
            unsigned long long m = __ballot(a);
            if (a) { int r = __popcll(m & ((1ull<<tid)-1ull)); alist[r] = tid; }
            if (tid == 0) nact_s = __popcll(m);
        }
    } else {
        if (tid < 48) alist[tid] = tid;
        if (tid == 0) nact_s = 48;
    }
    size_t obase = ((size_t)b*VV + rowv)*COUT;
    if (COMPACT) {
        for (int i = tid; i < 48*COUT; i += blockDim.x) out[obase + i] = 0.f;
    }
    __syncthreads();
    int nact = nact_s;
    int v = tid >> 5, co = tid & 31;
    for (int bs = 0; bs < nact; bs += 8) {
        int ai = bs + v;
        if (ai < nact) {
            int z = alist[ai];
            float acc = conv_acc<C1>(in, w, b, x, y, z, co);
            if (RELU) acc = fmaxf(acc, 0.f);
            if (!COMPACT) { if (!mask[(size_t)b*VV + rowv + z]) acc = 0.f; }
            out[obase + (size_t)z*COUT + co] = acc;
        }
    }
}

// ---------------- final conv computed directly at the gathered voxels -> d_out ----------------
__global__ void conv5_k(const float* __restrict__ in, const float* __restrict__ w,
                        const int* __restrict__ oidx, const int* __restrict__ nout,
                        float* __restrict__ out)
{
    int blk = blockIdx.x;                 // BB * (MAXF/8)
    int b = blk / (MAXF/8);
    int sbase = (blk % (MAXF/8)) * 8;
    int tid = threadIdx.x;
    int v = tid >> 5, co = tid & 31;
    int slot = sbase + v;
    float acc = 0.f;
    if (slot < nout[b]) {
        int vox = oidx[b*MAXF + slot];
        int x = vox / 2304, y = (vox % 2304) / 48, z = vox % 48;
        acc = conv_acc<32>(in, w, b, x, y, z, co);
    }
    out[((size_t)b*MAXF + slot)*COUT + co] = acc;
}

extern "C" void kernel_launch(void* const* d_in, const int* in_sizes, int n_in,
                              void* d_out, int out_size, void* d_ws, size_t ws_size,
                              hipStream_t stream)
{
    const float* feat   = (const float*)d_in[0];
    const int*   coords = (const int*)d_in[1];
    const float* w1 = (const float*)d_in[2];
    const float* w2 = (const float*)d_in[3];
    const float* w3 = (const float*)d_in[4];
    const float* w4 = (const float*)d_in[5];
    const float* w5 = (const float*)d_in[6];
    float* out = (float*)d_out;

    char* ws = (char*)d_ws;
    size_t off = 0;
    auto carve = [&](size_t bytes)->char* {
        char* p = ws + off; off = align_up(off + bytes, 256); return p;
    };
    int*           winner = (int*)carve((size_t)BB*VV*4);
    unsigned char* occ0   = (unsigned char*)carve((size_t)BB*VV);
    unsigned char* occ1   = (unsigned char*)carve((size_t)BB*VV);
    unsigned char* occ2   = (unsigned char*)carve((size_t)BB*VV);
    int*           counts = (int*)carve(BB*48*4);
    int*           sbase  = (int*)carve(BB*48*4);
    int*           nout   = (int*)carve(BB*4);
    int*           xl5    = (int*)carve(BB*4);
    int*           oidx   = (int*)carve((size_t)BB*MAXF*4);
    float*         grid0  = (float*)carve((size_t)BB*VV*16*4);
    float*         bufA   = (float*)carve((size_t)BB*VV*32*4);
    float*         bufB   = (float*)carve((size_t)BB*VV*32*4);
    (void)ws_size; (void)in_sizes; (void)n_in; (void)out_size;

    hipMemsetAsync(winner, 0xFF, (size_t)BB*VV*4, stream);   // winner = -1
    hipMemsetAsync(occ0, 0, (size_t)BB*VV, stream);
    hipMemsetAsync(grid0, 0, (size_t)BB*VV*16*4, stream);

    int nb = (BB*NPTS + 255)/256;
    scatter_winner_k<<<nb, 256, 0, stream>>>(coords, winner);
    scatter_write_k <<<nb, 256, 0, stream>>>(coords, feat, winner, grid0, occ0);

    int vb = (BB*VV + 255)/256;
    dilate_k<<<vb, 256, 0, stream>>>(occ0, occ1);
    dilate_k<<<vb, 256, 0, stream>>>(occ1, occ2);

    slice_count_k<<<BB*48, 256, 0, stream>>>(occ2, counts);
    prefix_k<<<1, 64, 0, stream>>>(counts, sbase, nout, xl5);
    compact_k<<<BB*48, 256, 0, stream>>>(occ2, sbase, oidx);

    dim3 cgrid(48, 48, BB);
    conv_k<16, true,  true ><<<cgrid, 256, 0, stream>>>(grid0, bufA, w1, occ0, xl5, 4);
    conv_k<32, true,  true ><<<cgrid, 256, 0, stream>>>(bufA,  bufB, w2, occ0, xl5, 3);
    conv_k<32, true,  true ><<<cgrid, 256, 0, stream>>>(bufB,  bufA, w3, occ0, xl5, 2);
    conv_k<32, true,  false><<<cgrid, 256, 0, stream>>>(bufA,  bufB, w4, occ1, xl5, 1);

    conv5_k<<<BB*(MAXF/8), 256, 0, stream>>>(bufB, w5, oidx, nout, out);
}

// Round 2
// 352.162 us; speedup vs baseline: 1.3272x; 1.3272x over previous
//
#include <hip/hip_runtime.h>

typedef unsigned long long u64;

#define VV 110592            // 48^3
#define BB 2
#define NPTS 20000
#define MAXF 5000

static inline size_t align_up(size_t v, size_t a){ return (v + a - 1) & ~(a - 1); }

// ---------------- scatter pass 1: winner (last point wins) + occupancy bitmask ----------------
__global__ void scatter1_k(const int* __restrict__ coords, int* __restrict__ winner,
                           u64* __restrict__ occm0)
{
    int t = blockIdx.x*blockDim.x + threadIdx.x;
    if (t >= BB*NPTS) return;
    int b = t / NPTS, n = t - b*NPTS;
    const int* c = coords + (size_t)t*3;
    int x = c[0], y = c[1], z = c[2];
    atomicMax(&winner[b*VV + (x*48+y)*48 + z], n);
    atomicOr(&occm0[b*2304 + x*48 + y], 1ull << z);
}

// ---------------- scatter pass 2: winner-only feature write ----------------
__global__ void scatter_write_k(const int* __restrict__ coords, const float* __restrict__ feat,
                                const int* __restrict__ winner, float* __restrict__ grid0)
{
    int t = blockIdx.x*blockDim.x + threadIdx.x;
    if (t >= BB*NPTS) return;
    int b = t / NPTS, n = t - b*NPTS;
    const int* c = coords + (size_t)t*3;
    int vox = (c[0]*48 + c[1])*48 + c[2];
    int gi = b*VV + vox;
    if (winner[gi] == n) {
        const float4* f = (const float4*)(feat + (size_t)t*16);
        float4* g = (float4*)(grid0 + (size_t)gi*16);
        g[0]=f[0]; g[1]=f[1]; g[2]=f[2]; g[3]=f[3];
    }
}

// ---------------- 3x3x3 dilation on z-bitmasks ----------------
__global__ void dilate_mask_k(const u64* __restrict__ in, u64* __restrict__ out)
{
    int t = blockIdx.x*blockDim.x + threadIdx.x;
    if (t >= BB*2304) return;
    int b = t / 2304, r = t - b*2304;
    int x = r / 48, y = r - x*48;
    u64 acc = 0;
    for (int dx=-1; dx<=1; ++dx){ int xx=x+dx; if ((unsigned)xx >= 48u) continue;
      for (int dy=-1; dy<=1; ++dy){ int yy=y+dy; if ((unsigned)yy >= 48u) continue;
        u64 m = in[b*2304 + xx*48 + yy];
        acc |= m | (m<<1) | (m>>1);
      }}
    out[t] = acc & ((1ull<<48) - 1ull);
}

// ---------------- per-x counts, prefixes, xl, per-layer site counts ----------------
__global__ void stats_k(const u64* __restrict__ m0, const u64* __restrict__ m1,
                        const u64* __restrict__ m2,
                        int* __restrict__ base0, int* __restrict__ base1, int* __restrict__ base2,
                        int* __restrict__ nsite, int* __restrict__ nout, int* __restrict__ xl5)
{
    __shared__ int c0[96], c1[96], c2[96];
    int t = threadIdx.x;
    if (t < 96) {
        int s0=0, s1=0, s2=0;
        for (int y=0; y<48; ++y) {
            s0 += __popcll(m0[t*48+y]);
            s1 += __popcll(m1[t*48+y]);
            s2 += __popcll(m2[t*48+y]);
        }
        c0[t]=s0; c1[t]=s1; c2[t]=s2;
    }
    __syncthreads();
    if (t < BB) {
        int b = t;
        int run0=0, run1=0, run2=0;
        int cum2[48];
        for (int x=0; x<48; ++x) {
            base0[b*48+x] = run0; run0 += c0[b*48+x];
            base1[b*48+x] = run1; run1 += c1[b*48+x];
            base2[b*48+x] = run2; run2 += c2[b*48+x];
            cum2[x] = run2;
        }
        int nsel = run2 < MAXF ? run2 : MAXF;
        int xl = 0;
        for (int x=0; x<48; ++x) { if (cum2[x] >= nsel) { xl = x; break; } }
        if (nsel == 0) xl = 0;
        nout[b] = nsel; xl5[b] = xl;
        int lim, s;
        lim = xl+4; if (lim>47) lim=47; s=0; for (int x=0;x<=lim;++x) s+=c0[b*48+x]; nsite[0*2+b]=s;
        lim = xl+3; if (lim>47) lim=47; s=0; for (int x=0;x<=lim;++x) s+=c0[b*48+x]; nsite[1*2+b]=s;
        lim = xl+2; if (lim>47) lim=47; s=0; for (int x=0;x<=lim;++x) s+=c0[b*48+x]; nsite[2*2+b]=s;
        lim = xl+1; if (lim>47) lim=47; s=0; for (int x=0;x<=lim;++x) s+=c1[b*48+x]; nsite[3*2+b]=s;
    }
}

// ---------------- ordered compaction of bitmask actives into site lists ----------------
__device__ __forceinline__ void compact_one(const u64* __restrict__ mask, const int* __restrict__ base,
                                            int* __restrict__ list, int b, int x, int t,
                                            int xlim, int cap, int* cnts)
{
    if (x <= xlim) {
        u64 m = (t < 48) ? mask[b*2304 + x*48 + t] : 0ull;
        if (t < 48) cnts[t] = __popcll(m);
        __syncthreads();
        if (t < 48) {
            int off = base[b*48 + x];
            for (int y=0; y<t; ++y) off += cnts[y];
            while (m) {
                int z = __builtin_ctzll(m); m &= m - 1;
                if (off < cap) list[off] = x*2304 + t*48 + z;
                ++off;
            }
        }
        __syncthreads();
    }
}

__global__ void compact_all_k(const u64* __restrict__ m0, const u64* __restrict__ m1,
                              const u64* __restrict__ m2,
                              const int* __restrict__ base0, const int* __restrict__ base1,
                              const int* __restrict__ base2,
                              const int* __restrict__ xl5, const int* __restrict__ nout,
                              int* __restrict__ list0, int* __restrict__ list1,
                              int* __restrict__ oidx)
{
    int b = blockIdx.x / 48, x = blockIdx.x % 48, t = threadIdx.x;
    __shared__ int cnts[48];
    int xl = xl5[b];
    int l0 = xl+4; if (l0>47) l0=47;
    int l1 = xl+1; if (l1>47) l1=47;
    compact_one(m0, base0, list0 + b*VV,   b, x, t, l0, 0x7fffffff, cnts);
    compact_one(m1, base1, list1 + b*VV,   b, x, t, l1, 0x7fffffff, cnts);
    compact_one(m2, base2, oidx  + b*MAXF, b, x, t, xl, nout[b],    cnts);
}

// ---------------- slab-bounded zero fill of conv buffers ----------------
__global__ void zero_k(float* __restrict__ grid0, float* __restrict__ bufA,
                       float* __restrict__ bufB, const int* __restrict__ xl5)
{
    int y = blockIdx.x, x = blockIdx.y, b = blockIdx.z;
    int xl = xl5[b];
    int gl = xl+5; if (gl>47) gl=47;
    int bl = xl+4; if (bl>47) bl=47;
    size_t rb = (size_t)b*VV + x*2304 + y*48;
    int tid = threadIdx.x;
    if (x <= gl) {
        float4* p = (float4*)(grid0 + rb*16);
        for (int i = tid; i < 192; i += 256) p[i] = make_float4(0,0,0,0);
    }
    if (x <= bl) {
        float4* pa = (float4*)(bufA + rb*32);
        float4* pb = (float4*)(bufB + rb*32);
        for (int i = tid; i < 384; i += 256) { pa[i] = make_float4(0,0,0,0); pb[i] = make_float4(0,0,0,0); }
    }
}

// ---------------- conv core: one thread = (site, 4 couts) ----------------
template<int C1>
__device__ __forceinline__ float4 conv_body(const float* __restrict__ inb, const float* __restrict__ w,
                                            int x, int y, int z, int co4)
{
    float4 acc = make_float4(0.f,0.f,0.f,0.f);
    for (int dx=0; dx<3; ++dx){ int xx = x+dx-1; if ((unsigned)xx >= 48u) continue;
      for (int dy=0; dy<3; ++dy){ int yy = y+dy-1; if ((unsigned)yy >= 48u) continue;
        const float* ip0 = inb + (size_t)(xx*48+yy)*48*C1;
        for (int dz=0; dz<3; ++dz){ int zz = z+dz-1; if ((unsigned)zz >= 48u) continue;
            const float* ip = ip0 + (size_t)zz*C1;
            const float* wp = w + (size_t)((dx*3+dy)*3+dz)*C1*32 + co4;
            #pragma unroll
            for (int c4=0; c4<C1/4; ++c4) {
                float4 iv = *(const float4*)(ip + c4*4);
                float4 w0 = *(const float4*)(wp + (c4*4+0)*32);
                float4 w1 = *(const float4*)(wp + (c4*4+1)*32);
                float4 w2 = *(const float4*)(wp + (c4*4+2)*32);
                float4 w3 = *(const float4*)(wp + (c4*4+3)*32);
                acc.x = fmaf(iv.x,w0.x, fmaf(iv.y,w1.x, fmaf(iv.z,w2.x, fmaf(iv.w,w3.x, acc.x))));
                acc.y = fmaf(iv.x,w0.y, fmaf(iv.y,w1.y, fmaf(iv.z,w2.y, fmaf(iv.w,w3.y, acc.y))));
                acc.z = fmaf(iv.x,w0.z, fmaf(iv.y,w1.z, fmaf(iv.z,w2.z, fmaf(iv.w,w3.z, acc.z))));
                acc.w = fmaf(iv.x,w0.w, fmaf(iv.y,w1.w, fmaf(iv.z,w2.w, fmaf(iv.w,w3.w, acc.w))));
            }
        }}}
    return acc;
}

// layers 1-4: grid-stride over combined (b0,b1) site list
template<int C1, bool RELU>
__global__ __launch_bounds__(256) void conv_sites_k(const float* __restrict__ in,
                                                    float* __restrict__ out,
                                                    const float* __restrict__ w,
                                                    const int* __restrict__ list,
                                                    const int* __restrict__ ns2)
{
    int n0 = ns2[0], ntot = n0 + ns2[1];
    int co4 = (threadIdx.x & 7) * 4;
    int slot0 = blockIdx.x*32 + (threadIdx.x >> 3);
    for (int s = slot0; s < ntot; s += gridDim.x*32) {
        int b = (s >= n0) ? 1 : 0;
        int vox = list[b*VV + (s - b*n0)];
        int x = vox / 2304; int rem = vox - x*2304; int y = rem / 48; int z = rem - y*48;
        float4 acc = conv_body<C1>(in + (size_t)b*VV*C1, w, x, y, z, co4);
        if (RELU) {
            acc.x = fmaxf(acc.x, 0.f); acc.y = fmaxf(acc.y, 0.f);
            acc.z = fmaxf(acc.z, 0.f); acc.w = fmaxf(acc.w, 0.f);
        }
        *(float4*)(out + ((size_t)b*VV + vox)*32 + co4) = acc;
    }
}

// layer 5: compute at the gathered first-MAXF voxels, write d_out directly
__global__ __launch_bounds__(256) void conv5_k(const float* __restrict__ in,
                                               const float* __restrict__ w,
                                               const int* __restrict__ oidx,
                                               const int* __restrict__ nout,
                                               float* __restrict__ out)
{
    int slot = blockIdx.x*32 + (threadIdx.x >> 3);
    if (slot >= BB*MAXF) return;
    int b = slot / MAXF, sl = slot - b*MAXF;
    int co4 = (threadIdx.x & 7) * 4;
    float4 acc = make_float4(0.f,0.f,0.f,0.f);
    if (sl < nout[b]) {
        int vox = oidx[b*MAXF + sl];
        int x = vox / 2304; int rem = vox - x*2304; int y = rem / 48; int z = rem - y*48;
        acc = conv_body<32>(in + (size_t)b*VV*32, w, x, y, z, co4);
    }
    *(float4*)(out + ((size_t)b*MAXF + sl)*32 + co4) = acc;
}

extern "C" void kernel_launch(void* const* d_in, const int* in_sizes, int n_in,
                              void* d_out, int out_size, void* d_ws, size_t ws_size,
                              hipStream_t stream)
{
    const float* feat   = (const float*)d_in[0];
    const int*   coords = (const int*)d_in[1];
    const float* w1 = (const float*)d_in[2];
    const float* w2 = (const float*)d_in[3];
    const float* w3 = (const float*)d_in[4];
    const float* w4 = (const float*)d_in[5];
    const float* w5 = (const float*)d_in[6];
    float* out = (float*)d_out;
    (void)in_sizes; (void)n_in; (void)out_size; (void)ws_size;

    char* ws = (char*)d_ws;
    size_t off = 0;
    auto carve = [&](size_t bytes)->char* { char* p = ws + off; off = align_up(off + bytes, 256); return p; };

    int*   winner = (int*)carve((size_t)BB*VV*4);
    u64*   occm0  = (u64*)carve((size_t)BB*2304*8);
    u64*   occm1  = (u64*)carve((size_t)BB*2304*8);
    u64*   occm2  = (u64*)carve((size_t)BB*2304*8);
    int*   base0  = (int*)carve(BB*48*4);
    int*   base1  = (int*)carve(BB*48*4);
    int*   base2  = (int*)carve(BB*48*4);
    int*   nsite  = (int*)carve(16*4);
    int*   nout   = (int*)carve(BB*4);
    int*   xl5    = (int*)carve(BB*4);
    int*   list0  = (int*)carve((size_t)BB*VV*4);
    int*   list1  = (int*)carve((size_t)BB*VV*4);
    int*   oidx   = (int*)carve((size_t)BB*MAXF*4);
    float* grid0  = (float*)carve((size_t)BB*VV*16*4);
    float* bufA   = (float*)carve((size_t)BB*VV*32*4);
    float* bufB   = (float*)carve((size_t)BB*VV*32*4);

    hipMemsetAsync(winner, 0xFF, (size_t)BB*VV*4, stream);
    hipMemsetAsync(occm0, 0, (size_t)BB*2304*8, stream);

    int nb = (BB*NPTS + 255)/256;
    scatter1_k<<<nb, 256, 0, stream>>>(coords, winner, occm0);

    int mb = (BB*2304 + 255)/256;
    dilate_mask_k<<<mb, 256, 0, stream>>>(occm0, occm1);
    dilate_mask_k<<<mb, 256, 0, stream>>>(occm1, occm2);

    stats_k<<<1, 128, 0, stream>>>(occm0, occm1, occm2, base0, base1, base2, nsite, nout, xl5);
    compact_all_k<<<BB*48, 64, 0, stream>>>(occm0, occm1, occm2, base0, base1, base2,
                                            xl5, nout, list0, list1, oidx);

    zero_k<<<dim3(48,48,BB), 256, 0, stream>>>(grid0, bufA, bufB, xl5);
    scatter_write_k<<<nb, 256, 0, stream>>>(coords, feat, winner, grid0);

    conv_sites_k<16, true><<<640, 256, 0, stream>>>(grid0, bufA, w1, list0, nsite + 0);
    conv_sites_k<32, true><<<640, 256, 0, stream>>>(bufA,  bufB, w2, list0, nsite + 2);
    conv_sites_k<32, true><<<640, 256, 0, stream>>>(bufB,  bufA, w3, list0, nsite + 4);
    conv_sites_k<32, true><<<640, 256, 0, stream>>>(bufA,  bufB, w4, list1, nsite + 6);

    conv5_k<<<(BB*MAXF + 31)/32, 256, 0, stream>>>(bufB, w5, oidx, nout, out);
}

// Round 3
// 253.054 us; speedup vs baseline: 1.8470x; 1.3916x over previous
//
#include <hip/hip_runtime.h>

typedef unsigned long long u64;

#define VV 110592            // 48^3
#define BB 2
#define NPTS 20000
#define MAXF 5000

static inline size_t align_up(size_t v, size_t a){ return (v + a - 1) & ~(a - 1); }

// ---------------- scatter pass 1: winner (last point wins) + occupancy bitmask ----------------
__global__ void scatter1_k(const int* __restrict__ coords, int* __restrict__ winner,
                           u64* __restrict__ occm0)
{
    int t = blockIdx.x*blockDim.x + threadIdx.x;
    if (t >= BB*NPTS) return;
    int b = t / NPTS, n = t - b*NPTS;
    const int* c = coords + (size_t)t*3;
    int x = c[0], y = c[1], z = c[2];
    atomicMax(&winner[b*VV + (x*48+y)*48 + z], n);
    atomicOr(&occm0[b*2304 + x*48 + y], 1ull << z);
}

// ---------------- scatter pass 2: winner-only feature write ----------------
__global__ void scatter_write_k(const int* __restrict__ coords, const float* __restrict__ feat,
                                const int* __restrict__ winner, float* __restrict__ grid0)
{
    int t = blockIdx.x*blockDim.x + threadIdx.x;
    if (t >= BB*NPTS) return;
    int b = t / NPTS, n = t - b*NPTS;
    const int* c = coords + (size_t)t*3;
    int vox = (c[0]*48 + c[1])*48 + c[2];
    int gi = b*VV + vox;
    if (winner[gi] == n) {
        const float4* f = (const float4*)(feat + (size_t)t*16);
        float4* g = (float4*)(grid0 + (size_t)gi*16);
        g[0]=f[0]; g[1]=f[1]; g[2]=f[2]; g[3]=f[3];
    }
}

// ---------------- 3x3x3 dilation on z-bitmasks ----------------
__global__ void dilate_mask_k(const u64* __restrict__ in, u64* __restrict__ out)
{
    int t = blockIdx.x*blockDim.x + threadIdx.x;
    if (t >= BB*2304) return;
    int b = t / 2304, r = t - b*2304;
    int x = r / 48, y = r - x*48;
    u64 acc = 0;
    for (int dx=-1; dx<=1; ++dx){ int xx=x+dx; if ((unsigned)xx >= 48u) continue;
      for (int dy=-1; dy<=1; ++dy){ int yy=y+dy; if ((unsigned)yy >= 48u) continue;
        u64 m = in[b*2304 + xx*48 + yy];
        acc |= m | (m<<1) | (m>>1);
      }}
    out[t] = acc & ((1ull<<48) - 1ull);
}

// ---------------- per-x counts, prefixes, xl, per-layer site counts ----------------
__global__ void stats_k(const u64* __restrict__ m0, const u64* __restrict__ m1,
                        const u64* __restrict__ m2,
                        int* __restrict__ base0, int* __restrict__ base1, int* __restrict__ base2,
                        int* __restrict__ nsite, int* __restrict__ nout, int* __restrict__ xl5)
{
    __shared__ int c0[96], c1[96], c2[96];
    int t = threadIdx.x;
    if (t < 96) {
        int s0=0, s1=0, s2=0;
        for (int y=0; y<48; ++y) {
            s0 += __popcll(m0[t*48+y]);
            s1 += __popcll(m1[t*48+y]);
            s2 += __popcll(m2[t*48+y]);
        }
        c0[t]=s0; c1[t]=s1; c2[t]=s2;
    }
    __syncthreads();
    if (t < BB) {
        int b = t;
        int run0=0, run1=0, run2=0;
        int cum2[48];
        for (int x=0; x<48; ++x) {
            base0[b*48+x] = run0; run0 += c0[b*48+x];
            base1[b*48+x] = run1; run1 += c1[b*48+x];
            base2[b*48+x] = run2; run2 += c2[b*48+x];
            cum2[x] = run2;
        }
        int nsel = run2 < MAXF ? run2 : MAXF;
        int xl = 0;
        for (int x=0; x<48; ++x) { if (cum2[x] >= nsel) { xl = x; break; } }
        if (nsel == 0) xl = 0;
        nout[b] = nsel; xl5[b] = xl;
        int lim, s;
        lim = xl+4; if (lim>47) lim=47; s=0; for (int x=0;x<=lim;++x) s+=c0[b*48+x]; nsite[0*2+b]=s;
        lim = xl+3; if (lim>47) lim=47; s=0; for (int x=0;x<=lim;++x) s+=c0[b*48+x]; nsite[1*2+b]=s;
        lim = xl+2; if (lim>47) lim=47; s=0; for (int x=0;x<=lim;++x) s+=c0[b*48+x]; nsite[2*2+b]=s;
        lim = xl+1; if (lim>47) lim=47; s=0; for (int x=0;x<=lim;++x) s+=c1[b*48+x]; nsite[3*2+b]=s;
    }
}

// ---------------- ordered compaction of bitmask actives into site lists ----------------
__device__ __forceinline__ void compact_one(const u64* __restrict__ mask, const int* __restrict__ base,
                                            int* __restrict__ list, int b, int x, int t,
                                            int xlim, int cap, int* cnts)
{
    if (x <= xlim) {
        u64 m = (t < 48) ? mask[b*2304 + x*48 + t] : 0ull;
        if (t < 48) cnts[t] = __popcll(m);
        __syncthreads();
        if (t < 48) {
            int off = base[b*48 + x];
            for (int y=0; y<t; ++y) off += cnts[y];
            while (m) {
                int z = __builtin_ctzll(m); m &= m - 1;
                if (off < cap) list[off] = x*2304 + t*48 + z;
                ++off;
            }
        }
        __syncthreads();
    }
}

__global__ void compact_all_k(const u64* __restrict__ m0, const u64* __restrict__ m1,
                              const u64* __restrict__ m2,
                              const int* __restrict__ base0, const int* __restrict__ base1,
                              const int* __restrict__ base2,
                              const int* __restrict__ xl5, const int* __restrict__ nout,
                              int* __restrict__ list0, int* __restrict__ list1,
                              int* __restrict__ oidx)
{
    int b = blockIdx.x / 48, x = blockIdx.x % 48, t = threadIdx.x;
    __shared__ int cnts[48];
    int xl = xl5[b];
    int l0 = xl+4; if (l0>47) l0=47;
    int l1 = xl+1; if (l1>47) l1=47;
    compact_one(m0, base0, list0 + b*VV,   b, x, t, l0, 0x7fffffff, cnts);
    compact_one(m1, base1, list1 + b*VV,   b, x, t, l1, 0x7fffffff, cnts);
    compact_one(m2, base2, oidx  + b*MAXF, b, x, t, xl, nout[b],    cnts);
}

// ---------------- slab-bounded zero fill of conv buffers ----------------
__global__ void zero_k(float* __restrict__ grid0, float* __restrict__ bufA,
                       float* __restrict__ bufB, const int* __restrict__ xl5)
{
    int y = blockIdx.x, x = blockIdx.y, b = blockIdx.z;
    int xl = xl5[b];
    int gl = xl+5; if (gl>47) gl=47;
    int bl = xl+4; if (bl>47) bl=47;
    size_t rb = (size_t)b*VV + x*2304 + y*48;
    int tid = threadIdx.x;
    if (x <= gl) {
        float4* p = (float4*)(grid0 + rb*16);
        for (int i = tid; i < 192; i += 256) p[i] = make_float4(0,0,0,0);
    }
    if (x <= bl) {
        float4* pa = (float4*)(bufA + rb*32);
        float4* pb = (float4*)(bufB + rb*32);
        for (int i = tid; i < 384; i += 256) { pa[i] = make_float4(0,0,0,0); pb[i] = make_float4(0,0,0,0); }
    }
}

// ---------------- partial conv over one dx-slice, tap-skipped via z-bitmask ----------------
template<int C1>
__device__ __forceinline__ float4 conv_part(const float* __restrict__ inb,   // batch input base
                                            const float* __restrict__ w,
                                            const u64* __restrict__ mb,     // batch mask base
                                            int x, int y, int z, int co4, int dxg)
{
    float4 acc = make_float4(0.f,0.f,0.f,0.f);
    int xx = x + dxg - 1;
    if ((unsigned)xx >= 48u) return acc;
    const float* inx = inb + (size_t)xx*2304*C1;
    const u64*  mrow = mb + xx*48;
    const float* wx  = w + (size_t)dxg*9*C1*32 + co4;
    for (int dy=0; dy<3; ++dy) {
        int yy = y + dy - 1;
        if ((unsigned)yy >= 48u) continue;
        unsigned zm = (unsigned)(((mrow[yy] << 1) >> z) & 7ull);   // active dz bits
        const float* iprow = inx + (size_t)yy*48*C1;
        const float* wy    = wx + (size_t)dy*3*C1*32;
        while (zm) {
            int dz = __builtin_ctz(zm); zm &= zm - 1;
            const float* ip = iprow + (size_t)(z+dz-1)*C1;
            const float* wp = wy + (size_t)dz*C1*32;
            #pragma unroll
            for (int c4=0; c4<C1/4; ++c4) {
                float4 iv = *(const float4*)(ip + c4*4);
                float4 w0 = *(const float4*)(wp + (c4*4+0)*32);
                float4 w1 = *(const float4*)(wp + (c4*4+1)*32);
                float4 w2 = *(const float4*)(wp + (c4*4+2)*32);
                float4 w3 = *(const float4*)(wp + (c4*4+3)*32);
                acc.x = fmaf(iv.x,w0.x, fmaf(iv.y,w1.x, fmaf(iv.z,w2.x, fmaf(iv.w,w3.x, acc.x))));
                acc.y = fmaf(iv.x,w0.y, fmaf(iv.y,w1.y, fmaf(iv.z,w2.y, fmaf(iv.w,w3.y, acc.y))));
                acc.z = fmaf(iv.x,w0.z, fmaf(iv.y,w1.z, fmaf(iv.z,w2.z, fmaf(iv.w,w3.z, acc.z))));
                acc.w = fmaf(iv.x,w0.w, fmaf(iv.y,w1.w, fmaf(iv.z,w2.w, fmaf(iv.w,w3.w, acc.w))));
            }
        }
    }
    return acc;
}

// ---------------- layers 1-4: thread = (site, co4, dx-group); LDS reduce over dx ----------------
template<int C1, bool RELU>
__global__ __launch_bounds__(384, 4) void conv_split_k(const float* __restrict__ in,
                                                       float* __restrict__ out,
                                                       const float* __restrict__ w,
                                                       const int* __restrict__ list,
                                                       const int* __restrict__ ns2,
                                                       const u64* __restrict__ masks)
{
    __shared__ float4 part[2][16][8];
    int tid = threadIdx.x;
    int dxg = tid >> 7;            // 0..2 (wave-uniform)
    int r   = tid & 127;
    int s   = r >> 3;              // site slot 0..15
    int coi = r & 7;               // co4 index
    int n0 = ns2[0], ntot = n0 + ns2[1];
    int nblk = (ntot + 15) >> 4;
    for (int blk = blockIdx.x; blk < nblk; blk += gridDim.x) {
        int si = blk*16 + s;
        bool valid = si < ntot;
        int b = 0, vox = 0;
        float4 acc = make_float4(0.f,0.f,0.f,0.f);
        if (valid) {
            b = (si >= n0) ? 1 : 0;
            vox = list[b*VV + (si - b*n0)];
            int x = vox / 2304; int rem = vox - x*2304; int y = rem / 48; int z = rem - y*48;
            acc = conv_part<C1>(in + (size_t)b*VV*C1, w, masks + b*2304, x, y, z, coi*4, dxg);
        }
        if (dxg > 0 && valid) part[dxg-1][s][coi] = acc;
        __syncthreads();
        if (dxg == 0 && valid) {
            float4 p1 = part[0][s][coi], p2 = part[1][s][coi];
            acc.x += p1.x + p2.x; acc.y += p1.y + p2.y;
            acc.z += p1.z + p2.z; acc.w += p1.w + p2.w;
            if (RELU) {
                acc.x = fmaxf(acc.x, 0.f); acc.y = fmaxf(acc.y, 0.f);
                acc.z = fmaxf(acc.z, 0.f); acc.w = fmaxf(acc.w, 0.f);
            }
            *(float4*)(out + ((size_t)b*VV + vox)*32 + coi*4) = acc;
        }
        __syncthreads();
    }
}

// ---------------- layer 5: same structure, gathered slots -> d_out ----------------
__global__ __launch_bounds__(384, 4) void conv5_split_k(const float* __restrict__ in,
                                                        const float* __restrict__ w,
                                                        const int* __restrict__ oidx,
                                                        const int* __restrict__ nout,
                                                        const u64* __restrict__ masks,
                                                        float* __restrict__ out)
{
    __shared__ float4 part[2][16][8];
    int tid = threadIdx.x;
    int dxg = tid >> 7;
    int r   = tid & 127;
    int s   = r >> 3;
    int coi = r & 7;
    int nblk = (BB*MAXF + 15) >> 4;
    for (int blk = blockIdx.x; blk < nblk; blk += gridDim.x) {
        int si = blk*16 + s;
        bool valid = si < BB*MAXF;
        int b = 0, sl = 0;
        float4 acc = make_float4(0.f,0.f,0.f,0.f);
        bool compute = false;
        if (valid) {
            b = si / MAXF; sl = si - b*MAXF;
            compute = sl < nout[b];
            if (compute) {
                int vox = oidx[b*MAXF + sl];
                int x = vox / 2304; int rem = vox - x*2304; int y = rem / 48; int z = rem - y*48;
                acc = conv_part<32>(in + (size_t)b*VV*32, w, masks + b*2304, x, y, z, coi*4, dxg);
            }
        }
        if (dxg > 0 && compute) part[dxg-1][s][coi] = acc;
        __syncthreads();
        if (dxg == 0 && valid) {
            if (compute) {
                float4 p1 = part[0][s][coi], p2 = part[1][s][coi];
                acc.x += p1.x + p2.x; acc.y += p1.y + p2.y;
                acc.z += p1.z + p2.z; acc.w += p1.w + p2.w;
            }
            *(float4*)(out + ((size_t)b*MAXF + sl)*32 + coi*4) = acc;
        }
        __syncthreads();
    }
}

extern "C" void kernel_launch(void* const* d_in, const int* in_sizes, int n_in,
                              void* d_out, int out_size, void* d_ws, size_t ws_size,
                              hipStream_t stream)
{
    const float* feat   = (const float*)d_in[0];
    const int*   coords = (const int*)d_in[1];
    const float* w1 = (const float*)d_in[2];
    const float* w2 = (const float*)d_in[3];
    const float* w3 = (const float*)d_in[4];
    const float* w4 = (const float*)d_in[5];
    const float* w5 = (const float*)d_in[6];
    float* out = (float*)d_out;
    (void)in_sizes; (void)n_in; (void)out_size; (void)ws_size;

    char* ws = (char*)d_ws;
    size_t off = 0;
    auto carve = [&](size_t bytes)->char* { char* p = ws + off; off = align_up(off + bytes, 256); return p; };

    int*   winner = (int*)carve((size_t)BB*VV*4);
    u64*   occm0  = (u64*)carve((size_t)BB*2304*8);
    u64*   occm1  = (u64*)carve((size_t)BB*2304*8);
    u64*   occm2  = (u64*)carve((size_t)BB*2304*8);
    int*   base0  = (int*)carve(BB*48*4);
    int*   base1  = (int*)carve(BB*48*4);
    int*   base2  = (int*)carve(BB*48*4);
    int*   nsite  = (int*)carve(16*4);
    int*   nout   = (int*)carve(BB*4);
    int*   xl5    = (int*)carve(BB*4);
    int*   list0  = (int*)carve((size_t)BB*VV*4);
    int*   list1  = (int*)carve((size_t)BB*VV*4);
    int*   oidx   = (int*)carve((size_t)BB*MAXF*4);
    float* grid0  = (float*)carve((size_t)BB*VV*16*4);
    float* bufA   = (float*)carve((size_t)BB*VV*32*4);
    float* bufB   = (float*)carve((size_t)BB*VV*32*4);

    hipMemsetAsync(winner, 0xFF, (size_t)BB*VV*4, stream);
    hipMemsetAsync(occm0, 0, (size_t)BB*2304*8, stream);

    int nb = (BB*NPTS + 255)/256;
    scatter1_k<<<nb, 256, 0, stream>>>(coords, winner, occm0);

    int mb = (BB*2304 + 255)/256;
    dilate_mask_k<<<mb, 256, 0, stream>>>(occm0, occm1);
    dilate_mask_k<<<mb, 256, 0, stream>>>(occm1, occm2);

    stats_k<<<1, 128, 0, stream>>>(occm0, occm1, occm2, base0, base1, base2, nsite, nout, xl5);
    compact_all_k<<<BB*48, 64, 0, stream>>>(occm0, occm1, occm2, base0, base1, base2,
                                            xl5, nout, list0, list1, oidx);

    zero_k<<<dim3(48,48,BB), 256, 0, stream>>>(grid0, bufA, bufB, xl5);
    scatter_write_k<<<nb, 256, 0, stream>>>(coords, feat, winner, grid0);

    conv_split_k<16, true><<<1536, 384, 0, stream>>>(grid0, bufA, w1, list0, nsite + 0, occm0);
    conv_split_k<32, true><<<1536, 384, 0, stream>>>(bufA,  bufB, w2, list0, nsite + 2, occm0);
    conv_split_k<32, true><<<1536, 384, 0, stream>>>(bufB,  bufA, w3, list0, nsite + 4, occm0);
    conv_split_k<32, true><<<1536, 384, 0, stream>>>(bufA,  bufB, w4, list1, nsite + 6, occm0);

    conv5_split_k<<<625, 384, 0, stream>>>(bufB, w5, oidx, nout, occm1, out);
}

// Round 4
// 188.370 us; speedup vs baseline: 2.4812x; 1.3434x over previous
//
#include <hip/hip_runtime.h>

typedef unsigned long long u64;
typedef __attribute__((ext_vector_type(8))) short s8v;
typedef __attribute__((ext_vector_type(4))) float f4v;

#define VV 110592            // 48^3
#define BB 2
#define NPTS 20000
#define MAXF 5000

static inline size_t align_up(size_t v, size_t a){ return (v + a - 1) & ~(a - 1); }

__device__ __forceinline__ int imin(int a, int b){ return a < b ? a : b; }

// round-to-nearest-even f32 -> bf16 bits
__device__ __forceinline__ unsigned rne16(float f){
    unsigned u = __float_as_uint(f);
    return (u + 0x7fffu + ((u >> 16) & 1u)) >> 16;
}
__device__ __forceinline__ float bf2f(unsigned h){ return __uint_as_float(h << 16); }

// ---------------- scatter pass 1: winner (last point wins) + occupancy bitmask ----------------
__global__ void scatter1_k(const int* __restrict__ coords, int* __restrict__ winner,
                           u64* __restrict__ occm0)
{
    int t = blockIdx.x*blockDim.x + threadIdx.x;
    if (t >= BB*NPTS) return;
    int b = t / NPTS, n = t - b*NPTS;
    const int* c = coords + (size_t)t*3;
    atomicMax(&winner[b*VV + (c[0]*48 + c[1])*48 + c[2]], n);
    atomicOr(&occm0[b*2304 + c[0]*48 + c[1]], 1ull << c[2]);
}

// ---------------- scatter pass 2: winner-only feature write as bf16 hi/lo planes ----------------
__global__ void scatter_write_k(const int* __restrict__ coords, const float* __restrict__ feat,
                                const int* __restrict__ winner,
                                unsigned short* __restrict__ gHi, unsigned short* __restrict__ gLo)
{
    int t = blockIdx.x*blockDim.x + threadIdx.x;
    if (t >= BB*NPTS) return;
    int b = t / NPTS, n = t - b*NPTS;
    const int* c = coords + (size_t)t*3;
    int vox = (c[0]*48 + c[1])*48 + c[2];
    int gi = b*VV + vox;
    if (winner[gi] != n) return;
    const float* f = feat + (size_t)t*16;
    size_t base = (size_t)gi*32;
    s8v hv[2], lv[2];
    #pragma unroll
    for (int ch = 0; ch < 2; ++ch) {
        #pragma unroll
        for (int j = 0; j < 8; ++j) {
            float v = f[ch*8 + j];
            unsigned hb = rne16(v);
            hv[ch][j] = (short)hb;
            lv[ch][j] = (short)rne16(v - bf2f(hb));
        }
        *(s8v*)&gHi[base + ch*8] = hv[ch];
        *(s8v*)&gLo[base + ch*8] = lv[ch];
    }
}

// ---------------- 3x3x3 dilation on z-bitmasks ----------------
__global__ void dilate_mask_k(const u64* __restrict__ in, u64* __restrict__ out)
{
    int t = blockIdx.x*blockDim.x + threadIdx.x;
    if (t >= BB*2304) return;
    int b = t / 2304, r = t - b*2304;
    int x = r / 48, y = r - x*48;
    u64 acc = 0;
    for (int dx=-1; dx<=1; ++dx){ int xx=x+dx; if ((unsigned)xx >= 48u) continue;
      for (int dy=-1; dy<=1; ++dy){ int yy=y+dy; if ((unsigned)yy >= 48u) continue;
        u64 m = in[b*2304 + xx*48 + yy];
        acc |= m | (m<<1) | (m>>1);
      }}
    out[t] = acc & ((1ull<<48) - 1ull);
}

// ---------------- occ2 stats: per-slice prefix, xl, nout, per-row output bases ----------------
__global__ void stats2_k(const u64* __restrict__ m2, int* __restrict__ nout,
                         int* __restrict__ xl5, int* __restrict__ rowbase2)
{
    __shared__ int c2[96];
    __shared__ int sb[96];
    int t = threadIdx.x;
    if (t < 96) {
        int s = 0;
        for (int y = 0; y < 48; ++y) s += __popcll(m2[t*48 + y]);
        c2[t] = s;
    }
    __syncthreads();
    if (t < BB) {
        int b = t, run = 0, xl = 0, nsel;
        int cum[48];
        for (int x = 0; x < 48; ++x) { sb[b*48+x] = run; run += c2[b*48+x]; cum[x] = run; }
        nsel = run < MAXF ? run : MAXF;
        for (int x = 0; x < 48; ++x) { if (cum[x] >= nsel) { xl = x; break; } }
        if (nsel == 0) xl = 0;
        nout[b] = nsel; xl5[b] = xl;
    }
    __syncthreads();
    if (t < 96) {
        int run = sb[t];
        for (int y = 0; y < 48; ++y) {
            rowbase2[t*48 + y] = run;
            run += __popcll(m2[t*48 + y]);
        }
    }
}

// ---------------- zero the grid bf16 planes over the needed slab ----------------
__global__ void zero_grid_k(unsigned short* __restrict__ gHi, unsigned short* __restrict__ gLo,
                            const int* __restrict__ xl5)
{
    int y = blockIdx.x, x = blockIdx.y, b = blockIdx.z;
    int lim = imin(47, xl5[b] + 5);
    if (x > lim) return;
    size_t base = ((size_t)b*VV + x*2304 + y*48) * 32;   // 48 z * 32 ci ushorts
    s8v z8 = {0,0,0,0,0,0,0,0};
    for (int i = threadIdx.x; i < 192; i += 256) {       // 192 chunks of 8 ushorts
        *(s8v*)&gHi[base + i*8] = z8;
        *(s8v*)&gLo[base + i*8] = z8;
    }
}

// ---------------- pack weights into per-lane B-fragment layout, bf16 hi/lo ----------------
// wpack layout: [layer][tap][half][plane][lane][8] bf16 (b128 per lane)
__global__ void wpack_k(const float* __restrict__ w1, const float* __restrict__ w2,
                        const float* __restrict__ w3, const float* __restrict__ w4,
                        const float* __restrict__ w5, short* __restrict__ wpack)
{
    int bid = blockIdx.x;                 // 5*27*2 = 270
    int layer = bid / 54;
    int r = bid % 54;
    int tap = r >> 1, half = r & 1;
    int lane = threadIdx.x;               // 64
    const float* w = layer==0 ? w1 : layer==1 ? w2 : layer==2 ? w3 : layer==3 ? w4 : w5;
    int cin = (layer == 0) ? 16 : 32;
    int n = half*16 + (lane & 15);
    s8v hv, lv;
    #pragma unroll
    for (int j = 0; j < 8; ++j) {
        int k = (lane >> 4)*8 + j;
        float v = (k < cin) ? w[((size_t)tap*cin + k)*32 + n] : 0.f;
        unsigned hb = rne16(v);
        hv[j] = (short)hb;
        lv[j] = (short)rne16(v - bf2f(hb));
    }
    size_t base = ((((size_t)(layer*27 + tap)*2 + half)*2 + 0)*64 + lane)*8;
    *(s8v*)&wpack[base] = hv;
    *(s8v*)&wpack[base + 64*8] = lv;      // plane=1 offset
}

// ---------------- MFMA conv layer over dense z-rows of the slab ----------------
// MODE 0: write bf16 hi/lo planes with ReLU + occ-mask.  MODE 1: final, gathered f32 -> d_out.
template<int MODE>
__global__ __launch_bounds__(192) void conv_mfma_k(
        const unsigned short* __restrict__ inHi, const unsigned short* __restrict__ inLo,
        const short* __restrict__ wp,            // this layer's wpack base
        const u64* __restrict__ omask, const int* __restrict__ xl5, int xoff,
        unsigned short* __restrict__ outHi, unsigned short* __restrict__ outLo,
        const int* __restrict__ rowbase2, const int* __restrict__ nout,
        float* __restrict__ outf)
{
    int y = blockIdx.x, x = blockIdx.y, b = blockIdx.z;
    int lim = imin(47, xl5[b] + xoff);
    if (x > lim) return;

    __shared__ short sA[2][3][4][400];   // [plane][dy][cichunk][50 z * 8 bf16] = 19.2 KB
    int tid = threadIdx.x;
    int lane = tid & 63;
    int wv = tid >> 6;                   // z-tile 0..2
    int c4 = lane >> 4, zr = lane & 15;

    f4v acc0 = {0.f,0.f,0.f,0.f};
    f4v acc1 = {0.f,0.f,0.f,0.f};
    const size_t inb = (size_t)b*VV*32;

    for (int dx = 0; dx < 3; ++dx) {
        __syncthreads();
        int xx = x + dx - 1;
        if ((unsigned)xx >= 48u) continue;
        // stage 3 y-rows (hi+lo), transposed [cichunk][z], z padded -1/48 with zeros
        for (int e = tid; e < 1200; e += 192) {
            int z = e % 50;
            int r = e / 50;
            int c = r & 3; r >>= 2;
            int dy = r % 3, pl = r / 3;
            int yy = y + dy - 1, zz = z - 1;
            s8v v = {0,0,0,0,0,0,0,0};
            if ((unsigned)yy < 48u && (unsigned)zz < 48u) {
                const unsigned short* src = (pl ? inLo : inHi) + inb
                    + ((size_t)((xx*48 + yy)*48 + zz)*32 + c*8);
                v = *(const s8v*)src;
            }
            *(s8v*)&sA[pl][dy][c][z*8] = v;
        }
        __syncthreads();
        for (int dy = 0; dy < 3; ++dy) {
            #pragma unroll
            for (int dz = 0; dz < 3; ++dz) {
                s8v Ah = *(const s8v*)&sA[0][dy][c4][(wv*16 + zr + dz)*8];
                s8v Al = *(const s8v*)&sA[1][dy][c4][(wv*16 + zr + dz)*8];
                int tap = (dx*3 + dy)*3 + dz;
                const s8v* wb = (const s8v*)(wp + (size_t)tap*2*2*64*8);
                s8v Bh0 = wb[(0*2+0)*64 + lane];
                s8v Bl0 = wb[(0*2+1)*64 + lane];
                s8v Bh1 = wb[(1*2+0)*64 + lane];
                s8v Bl1 = wb[(1*2+1)*64 + lane];
                acc0 = __builtin_amdgcn_mfma_f32_16x16x32_bf16(Ah, Bh0, acc0, 0, 0, 0);
                acc1 = __builtin_amdgcn_mfma_f32_16x16x32_bf16(Ah, Bh1, acc1, 0, 0, 0);
                acc0 = __builtin_amdgcn_mfma_f32_16x16x32_bf16(Ah, Bl0, acc0, 0, 0, 0);
                acc1 = __builtin_amdgcn_mfma_f32_16x16x32_bf16(Ah, Bl1, acc1, 0, 0, 0);
                acc0 = __builtin_amdgcn_mfma_f32_16x16x32_bf16(Al, Bh0, acc0, 0, 0, 0);
                acc1 = __builtin_amdgcn_mfma_f32_16x16x32_bf16(Al, Bh1, acc1, 0, 0, 0);
            }
        }
    }

    // epilogue: D layout col = lane&15 (co within half), row = (lane>>4)*4 + reg (z within tile)
    u64 om = omask[b*2304 + x*48 + y];
    int co_l = lane & 15, rg = lane >> 4;
    if (MODE == 0) {
        #pragma unroll
        for (int half = 0; half < 2; ++half) {
            f4v a = half ? acc1 : acc0;
            #pragma unroll
            for (int reg = 0; reg < 4; ++reg) {
                int z = wv*16 + rg*4 + reg;
                float v = fmaxf(a[reg], 0.f);
                if (!((om >> z) & 1ull)) v = 0.f;
                unsigned hb = rne16(v);
                unsigned lb = rne16(v - bf2f(hb));
                size_t o = inb + ((size_t)((x*48 + y)*48 + z))*32 + half*16 + co_l;
                outHi[o] = (unsigned short)hb;
                outLo[o] = (unsigned short)lb;
            }
        }
    } else {
        int nb_ = imin(nout[b], MAXF);
        int rb = rowbase2[(b*48 + x)*48 + y];
        #pragma unroll
        for (int half = 0; half < 2; ++half) {
            f4v a = half ? acc1 : acc0;
            #pragma unroll
            for (int reg = 0; reg < 4; ++reg) {
                int z = wv*16 + rg*4 + reg;
                if ((om >> z) & 1ull) {
                    int rank = __popcll(om & ((1ull << z) - 1ull));
                    int slot = rb + rank;
                    if (slot >= 0 && slot < nb_)
                        outf[((size_t)(b*MAXF + slot))*32 + half*16 + co_l] = a[reg];
                }
            }
        }
    }
}

extern "C" void kernel_launch(void* const* d_in, const int* in_sizes, int n_in,
                              void* d_out, int out_size, void* d_ws, size_t ws_size,
                              hipStream_t stream)
{
    const float* feat   = (const float*)d_in[0];
    const int*   coords = (const int*)d_in[1];
    const float* w1 = (const float*)d_in[2];
    const float* w2 = (const float*)d_in[3];
    const float* w3 = (const float*)d_in[4];
    const float* w4 = (const float*)d_in[5];
    const float* w5 = (const float*)d_in[6];
    float* out = (float*)d_out;
    (void)in_sizes; (void)n_in; (void)out_size; (void)ws_size;

    char* ws = (char*)d_ws;
    size_t off = 0;
    auto carve = [&](size_t bytes)->char* { char* p = ws + off; off = align_up(off + bytes, 256); return p; };

    int*  winner   = (int*)carve((size_t)BB*VV*4);
    u64*  occm0    = (u64*)carve((size_t)BB*2304*8);
    u64*  occm1    = (u64*)carve((size_t)BB*2304*8);
    u64*  occm2    = (u64*)carve((size_t)BB*2304*8);
    int*  nout     = (int*)carve(BB*4);
    int*  xl5      = (int*)carve(BB*4);
    int*  rowbase2 = (int*)carve(96*48*4);
    short* wpack   = (short*)carve((size_t)5*27*2*2*64*8*2);
    unsigned short* gHi = (unsigned short*)carve((size_t)BB*VV*32*2);
    unsigned short* gLo = (unsigned short*)carve((size_t)BB*VV*32*2);
    unsigned short* aHi = (unsigned short*)carve((size_t)BB*VV*32*2);
    unsigned short* aLo = (unsigned short*)carve((size_t)BB*VV*32*2);
    unsigned short* bHi = (unsigned short*)carve((size_t)BB*VV*32*2);
    unsigned short* bLo = (unsigned short*)carve((size_t)BB*VV*32*2);

    hipMemsetAsync(winner, 0xFF, (size_t)BB*VV*4, stream);
    hipMemsetAsync(occm0, 0, (size_t)BB*2304*8, stream);
    hipMemsetAsync(out, 0, (size_t)BB*MAXF*32*4, stream);

    int nb = (BB*NPTS + 255)/256;
    scatter1_k<<<nb, 256, 0, stream>>>(coords, winner, occm0);

    int mb = (BB*2304 + 255)/256;
    dilate_mask_k<<<mb, 256, 0, stream>>>(occm0, occm1);
    dilate_mask_k<<<mb, 256, 0, stream>>>(occm1, occm2);

    stats2_k<<<1, 128, 0, stream>>>(occm2, nout, xl5, rowbase2);

    zero_grid_k<<<dim3(48,48,BB), 256, 0, stream>>>(gHi, gLo, xl5);
    scatter_write_k<<<nb, 256, 0, stream>>>(coords, feat, winner, gHi, gLo);
    wpack_k<<<270, 64, 0, stream>>>(w1, w2, w3, w4, w5, wpack);

    const size_t LSZ = (size_t)27*2*2*64*8;   // shorts per layer in wpack
    dim3 cgrid(48, 48, BB);
    conv_mfma_k<0><<<cgrid, 192, 0, stream>>>(gHi, gLo, wpack + 0*LSZ, occm0, xl5, 4,
                                              aHi, aLo, nullptr, nullptr, nullptr);
    conv_mfma_k<0><<<cgrid, 192, 0, stream>>>(aHi, aLo, wpack + 1*LSZ, occm0, xl5, 3,
                                              bHi, bLo, nullptr, nullptr, nullptr);
    conv_mfma_k<0><<<cgrid, 192, 0, stream>>>(bHi, bLo, wpack + 2*LSZ, occm0, xl5, 2,
                                              aHi, aLo, nullptr, nullptr, nullptr);
    conv_mfma_k<0><<<cgrid, 192, 0, stream>>>(aHi, aLo, wpack + 3*LSZ, occm1, xl5, 1,
                                              bHi, bLo, nullptr, nullptr, nullptr);
    conv_mfma_k<1><<<cgrid, 192, 0, stream>>>(bHi, bLo, wpack + 4*LSZ, occm2, xl5, 0,
                                              nullptr, nullptr, rowbase2, nout, out);
}